// Round 9
// baseline (19.661 us; speedup 1.0000x reference)
//
#include <hip/hip_runtime.h>
#include <math.h>

// ---------------------------------------------------------------------------
// FashionNetLoss: 3-scale YOLO-ish loss.
//  * obj focal loss is a mean over ALL cells, but target is 0 except at the
//    512 occupied cells per scale -> sum focal(x,0) over all cells + per-
//    target correction focal(x,t)-focal(x,0).
//  * box & cls losses only touch the 512 target cells per scale; npos==512.
//
// R8 post-mortem: `old % gsz == gsz-1` on a NON-ZERO-START counter is
// exactly-once but NOT last-arrival -> finalizer read stale slots (absmax
// 20.4). Also, persistent counters violate the no-cross-call-state rule.
// R9: tiny prologue node zeroes the 17 counters every call (17 dirty lines
// -> negligible flush), so `old == gsz-1` / `o2 == 15` are TRUE last-arrival
// conditions. Publish chain unchanged from R7 (proven bit-exact):
// atomicExch slots -> s_waitcnt vmcnt(0) -> arrival RMW; finalizer reads
// slots via coherence-point atomicAdd(+0.0f). No spinning anywhere.
//
// Block map: [0,6) box (s=gid>>9), [6,84) cls (sk=(wid-6)>>1, s=sk/13),
//            [84,609) sweep chunks: [0,400)=s0, [400,500)=s1, [500,525)=s2.
// ws: float slots [2*wid, 2*wid+1]; uint counters: group g at uint idx
//     4096+g*32 (128B stride), global at 4608.
// ---------------------------------------------------------------------------

#define NBLK_BOX 6     // 1536 threads: one per (target,scale), ch0..4
#define NBLK_CLS 78    // 19968 threads: one per (target,scale,class)
#define NBLK_TGT (NBLK_BOX + NBLK_CLS)            // 84
#define NBLK_SWEEP 525 // 512 float4 per block, 2 per thread
#define NWORK (NBLK_TGT + NBLK_SWEEP)             // 609 blocks total
#define GCNT_IDX(g) (4096 + (g) * 32)             // uint idx, 128B stride
#define GLOB_IDX 4608                              // global counter uint idx

namespace {
// exact path (box blocks only)
__device__ __forceinline__ float bce_logits(float x, float t) {
    return fmaxf(x, 0.0f) - x * t + log1pf(expf(-fabsf(x)));
}
__device__ __forceinline__ float focal_term(float x, float t) {
    float b = bce_logits(x, t);
    float pt = expf(-b);
    float om = fmaxf(1.0f - pt, 0.0f);
    return 0.25f * om * sqrtf(om) * b;   // alpha=0.25, gamma=1.5
}
// fast path (sweep + cls): v_exp_f32 / v_log_f32 based
__device__ __forceinline__ float softplus_neg(float u) {  // log1p(exp(u)), u<=0
    return __logf(1.0f + __expf(u));
}
__device__ __forceinline__ float bce_fast(float x, float t) {
    return fmaxf(x, 0.0f) - x * t + softplus_neg(-fabsf(x));
}
__device__ __forceinline__ float focal0_fast(float x) {   // focal(x, 0)
    float b = fmaxf(x, 0.0f) + softplus_neg(-fabsf(x));
    float pt = __expf(-b);
    float om = fmaxf(1.0f - pt, 0.0f);
    return 0.25f * om * sqrtf(om) * b;
}
} // namespace

// Prologue node: zero the 16 group counters + global counter (every call).
__global__ void fnl_zero_cnt(unsigned* __restrict__ wsU) {
    int i = threadIdx.x;
    if (i < 16) wsU[GCNT_IDX(i)] = 0u;
    if (i == 16) wsU[GLOB_IDX] = 0u;
}

__global__ void __launch_bounds__(256) fnl_fused(
    const float* __restrict__ p0, const float* __restrict__ p1,
    const float* __restrict__ p2, const float* __restrict__ tg,
    float* __restrict__ ws, float* __restrict__ out) {
    __shared__ float sm0[4], sm1[4];
    __shared__ float red[12];
    __shared__ unsigned smFin;
    unsigned* wsU = reinterpret_cast<unsigned*>(ws);
    const float* const ps[3] = {p0, p1, p2};
    const int gss[3] = {160, 80, 40};
    const int wid = blockIdx.x;

    float v0 = 0.0f, v1 = 0.0f;   // per-thread partials for this block's slot

    if (wid < NBLK_BOX) {
        // ---- box + obj-correction: one thread per (target,scale) ----------
        int gid = wid * 256 + threadIdx.x;           // [0,1536)
        int s = gid >> 9;                            // block-uniform
        int t = gid & 511;

        const float bi  = tg[t * 6 + 0];
        const float cx  = tg[t * 6 + 2];
        const float cy  = tg[t * 6 + 3];
        const float w   = tg[t * 6 + 4];
        const float h   = tg[t * 6 + 5];
        const int b = (int)bi;

        const int gs = gss[s];
        const float fgs = (float)gs;
        float cxs = cx * fgs, cys = cy * fgs;
        int gi = (int)floorf(cxs); gi = min(max(gi, 0), gs - 1);
        int gj = (int)floorf(cys); gj = min(max(gj, 0), gs - 1);
        const float tx = cxs - (float)gi;
        const float ty = cys - (float)gj;
        const float tw = w * fgs;
        const float th = h * fgs;

        const int hw = gs * gs;
        const float* base = ps[s] + (size_t)b * 18 * hw + (size_t)gj * gs + gi;
        float pr0 = base[0];
        float pr1 = base[(size_t)hw];
        float pr2 = base[(size_t)2 * hw];
        float pr3 = base[(size_t)3 * hw];
        float pr4 = base[(size_t)4 * hw];

        const float px = 1.0f / (1.0f + expf(-pr0));
        const float py = 1.0f / (1.0f + expf(-pr1));
        const float pw = pr2;
        const float ph = pr3;

        const float eps = 1e-7f;
        float px1 = px - pw * 0.5f, px2 = px + pw * 0.5f;
        float py1 = py - ph * 0.5f, py2 = py + ph * 0.5f;
        float tx1 = tx - tw * 0.5f, tx2 = tx + tw * 0.5f;
        float ty1 = ty - th * 0.5f, ty2 = ty + th * 0.5f;
        float iw = fmaxf(fminf(px2, tx2) - fmaxf(px1, tx1), 0.0f);
        float ih = fmaxf(fminf(py2, ty2) - fmaxf(py1, ty1), 0.0f);
        float inter = iw * ih;
        float uni = pw * ph + tw * th - inter + eps;
        float iou = inter / uni;
        float ew = fmaxf(fmaxf(px2, tx2) - fminf(px1, tx1), 0.0f);
        float eh = fmaxf(fmaxf(py2, ty2) - fminf(py1, ty1), 0.0f);
        float c2 = ew * ew + eh * eh + eps;
        float rho2 = (px - tx) * (px - tx) + (py - ty) * (py - ty);
        const float four_over_pi2 = 0.405284734569351085775517852f;
        float dat = atanf(tw / (th + eps)) - atanf(pw / (ph + eps));
        float v = four_over_pi2 * dat * dat;
        float alpha = v / (1.0f - iou + v + eps);
        float ciou = iou - (rho2 / c2 + v * alpha);

        v0 = 1.0f - ciou;                                     // box
        float tobj = fmaxf(ciou, 0.0f);
        v1 = focal_term(pr4, tobj) - focal_term(pr4, 0.0f);   // obj corr
    } else if (wid < NBLK_TGT) {
        // ---- cls: one thread per (target,scale,class), 1 load each --------
        int g = (wid - NBLK_BOX) * 256 + threadIdx.x;
        int sk = g >> 9;          // block-uniform: (s*13 + k)
        int t  = g & 511;
        int s  = sk / 13;
        int k  = sk - s * 13;

        const float bi  = tg[t * 6 + 0];
        const float clf = tg[t * 6 + 1];
        const float cx  = tg[t * 6 + 2];
        const float cy  = tg[t * 6 + 3];
        const int b = (int)bi;
        const int cls = (int)clf;

        const int gs = gss[s];
        const float fgs = (float)gs;
        int gi = (int)floorf(cx * fgs); gi = min(max(gi, 0), gs - 1);
        int gj = (int)floorf(cy * fgs); gj = min(max(gj, 0), gs - 1);

        const int hw = gs * gs;
        float x = ps[s][(size_t)b * 18 * hw + (size_t)(5 + k) * hw +
                        (size_t)gj * gs + gi];
        float tc = (k == cls) ? 0.95f : 0.0f;
        v0 = bce_fast(x, tc);
    } else {
        // ---- focal(x,0) sweep: 512 float4 per block, 2 per thread ---------
        int chunk = wid - NBLK_TGT;                  // [0,525)
        const float* p;
        int hw4, base4;                              // block-uniform
        if (chunk < 400)      { p = p0; hw4 = 6400; base4 = 0; }
        else if (chunk < 500) { p = p1; hw4 = 1600; base4 = 204800; }
        else                  { p = p2; hw4 = 400;  base4 = 256000; }

        int j0 = chunk * 512 + threadIdx.x - base4;  // float4 idx in scale
        #pragma unroll
        for (int r = 0; r < 2; ++r) {
            int idx = j0 + r * 256;
            int b = idx / hw4;
            int pos4 = idx - b * hw4;
            int hw = hw4 * 4;
            const float4* src = reinterpret_cast<const float4*>(
                p + (size_t)b * 18 * hw + (size_t)4 * hw);
            float4 x = src[pos4];
            v0 += focal0_fast(x.x) + focal0_fast(x.y) +
                  focal0_fast(x.z) + focal0_fast(x.w);
        }
    }

    // ---- block reduce, publish, TRUE last-arrival detection ---------------
    for (int off = 32; off; off >>= 1) {
        v0 += __shfl_down(v0, off);
        v1 += __shfl_down(v1, off);
    }
    if ((threadIdx.x & 63) == 0) {
        sm0[threadIdx.x >> 6] = v0;
        sm1[threadIdx.x >> 6] = v1;
    }
    if (threadIdx.x == 0) smFin = 0u;
    __syncthreads();
    if (threadIdx.x == 0) {
        atomicExch(&ws[2 * wid + 0], sm0[0] + sm0[1] + sm0[2] + sm0[3]);
        atomicExch(&ws[2 * wid + 1], sm1[0] + sm1[1] + sm1[2] + sm1[3]);
        // slot exchs must be ack'd at the coherence point before arrival RMW
        asm volatile("s_waitcnt vmcnt(0)" ::: "memory");
        unsigned g = (unsigned)wid & 15u;
        unsigned gsz = (g == 0u) ? 39u : 38u;        // 609 = 39 + 15*38
        unsigned old = atomicAdd(&wsU[GCNT_IDX(g)], 1u);
        if (old == gsz - 1u) {                        // true last of group
            unsigned o2 = atomicAdd(&wsU[GLOB_IDX], 1u);
            if (o2 == 15u) smFin = 1u;                // true last group
        }
    }
    __syncthreads();
    if (!smFin) return;

    // ---- block-wide finalize (exactly one block per call) -----------------
    float a[12];   // [s*4 + {0:focal,1:box,2:cls,3:corr}]
    #pragma unroll
    for (int j = 0; j < 12; ++j) a[j] = 0.0f;

    for (int i = threadIdx.x; i < NWORK; i += 256) {
        float u0 = atomicAdd(&ws[2 * i + 0], 0.0f);  // coherence-point read
        float u1 = atomicAdd(&ws[2 * i + 1], 0.0f);
        if (i < NBLK_BOX) {
            int s = i >> 1;
            a[s * 4 + 1] += u0;
            a[s * 4 + 3] += u1;
        } else if (i < NBLK_TGT) {
            int sk = (i - NBLK_BOX) >> 1;
            int s = sk / 13;
            a[s * 4 + 2] += u0;
        } else {
            int chunk = i - NBLK_TGT;
            int s = (chunk < 400) ? 0 : ((chunk < 500) ? 1 : 2);
            a[s * 4 + 0] += u0;
        }
    }

    if (threadIdx.x < 12) red[threadIdx.x] = 0.0f;
    __syncthreads();
    #pragma unroll
    for (int j = 0; j < 12; ++j) {
        float v = a[j];
        for (int off = 32; off; off >>= 1) v += __shfl_down(v, off);
        if ((threadIdx.x & 63) == 0) atomicAdd(&red[j], v);   // LDS atomic
    }
    __syncthreads();

    if (threadIdx.x == 0) {
        const float cells[3] = {819200.0f, 204800.0f, 51200.0f};
        const float npos = 512.0f;
        float lb = 0.0f, lo = 0.0f, lc = 0.0f;
        for (int s = 0; s < 3; ++s) {
            lb += red[s * 4 + 1] / npos;
            lo += (red[s * 4 + 0] + red[s * 4 + 3]) / cells[s];
            lc += red[s * 4 + 2] / (npos * 13.0f);
        }
        out[0] = 5.0f * lb + 1.0f * lo + 0.5f * lc;
        out[1] = lb;
        out[2] = lo;
        out[3] = lc;
    }
}

extern "C" void kernel_launch(void* const* d_in, const int* in_sizes, int n_in,
                              void* d_out, int out_size, void* d_ws, size_t ws_size,
                              hipStream_t stream) {
    const float* p0 = (const float*)d_in[0];
    const float* p1 = (const float*)d_in[1];
    const float* p2 = (const float*)d_in[2];
    const float* tg = (const float*)d_in[3];
    float* ws = (float*)d_ws;
    float* out = (float*)d_out;

    fnl_zero_cnt<<<1, 64, 0, stream>>>((unsigned*)d_ws);
    fnl_fused<<<NWORK, 256, 0, stream>>>(p0, p1, p2, tg, ws, out);
}

// Round 10
// 14.807 us; speedup vs baseline: 1.3279x; 1.3279x over previous
//
#include <hip/hip_runtime.h>
#include <math.h>

// ---------------------------------------------------------------------------
// FashionNetLoss: 3-scale YOLO-ish loss.
//  * obj focal loss is a mean over ALL cells, but target is 0 except at the
//    512 occupied cells per scale -> sum focal(x,0) over all cells + per-
//    target correction focal(x,t)-focal(x,0).
//  * box & cls losses only touch the 512 target cells per scale; npos==512.
//
// R9 post-mortem: in-kernel finalize via device-scope atomics regressed AGAIN
// (+5us vs R6) — publish chain = same-line atomicExch x2 + vmcnt(0) coherence
// round-trip in every block + serial finalizer tail. Fusion via atomics is
// structurally more expensive than a finalize node on this chip (proven twice:
// R7 spin +4.5us, R9 arrival-tree +4.9us). Keep R6's 2-node shape.
// R10 trims within that shape:
//  * 609 -> 156 blocks (sweep 8 f4/thread for s0/s1, cls folded back into the
//    6 box blocks as 13 extra INDEPENDENT loads/thread — R4 proved gather
//    depth via independent loads is not the controlling variable).
//  * float4 slots: one coalesced 16B store per block; finalize reads 156
//    consecutive float4s (2.4KB, one coalesced latency round).
//  * zero global atomics anywhere (R5's lesson).
//
// Block map: [0,6) box+cls (s=wid>>1), [6,106) sweep s0 (2048 f4/blk),
//            [106,131) sweep s1 (2048 f4/blk), [131,156) sweep s2 (512).
// Slot: ws4[wid] = {box, corr, cls, 0} for box blocks, {focal,0,0,0} sweep.
// ---------------------------------------------------------------------------

#define NBLK_BOX 6
#define NBLK_S0 100    // 2048 float4/block, 8/thread
#define NBLK_S1 25     // 2048 float4/block, 8/thread
#define NBLK_S2 25     // 512 float4/block, 2/thread
#define NWORK (NBLK_BOX + NBLK_S0 + NBLK_S1 + NBLK_S2)   // 156

namespace {
// exact path (box blocks only)
__device__ __forceinline__ float bce_logits(float x, float t) {
    return fmaxf(x, 0.0f) - x * t + log1pf(expf(-fabsf(x)));
}
__device__ __forceinline__ float focal_term(float x, float t) {
    float b = bce_logits(x, t);
    float pt = expf(-b);
    float om = fmaxf(1.0f - pt, 0.0f);
    return 0.25f * om * sqrtf(om) * b;   // alpha=0.25, gamma=1.5
}
// fast path (sweep + cls): v_exp_f32 / v_log_f32 based
__device__ __forceinline__ float softplus_neg(float u) {  // log1p(exp(u)), u<=0
    return __logf(1.0f + __expf(u));
}
__device__ __forceinline__ float bce_fast(float x, float t) {
    return fmaxf(x, 0.0f) - x * t + softplus_neg(-fabsf(x));
}
__device__ __forceinline__ float focal0_fast(float x) {   // focal(x, 0)
    float b = fmaxf(x, 0.0f) + softplus_neg(-fabsf(x));
    float pt = __expf(-b);
    float om = fmaxf(1.0f - pt, 0.0f);
    return 0.25f * om * sqrtf(om) * b;
}
} // namespace

__global__ void __launch_bounds__(256) fnl_main(
    const float* __restrict__ p0, const float* __restrict__ p1,
    const float* __restrict__ p2, const float* __restrict__ tg,
    float4* __restrict__ ws4) {
    __shared__ float sm0[4], sm1[4], sm2[4];
    const int wid = blockIdx.x;

    float v0 = 0.0f, v1 = 0.0f, v2 = 0.0f;

    if (wid < NBLK_BOX) {
        // ---- box + obj-corr + cls: one thread per (target,scale) ----------
        const float* const ps[3] = {p0, p1, p2};
        const int gss[3] = {160, 80, 40};
        int gid = wid * 256 + threadIdx.x;           // [0,1536)
        int s = gid >> 9;                            // block-uniform (wid>>1)
        int t = gid & 511;

        const float bi  = tg[t * 6 + 0];
        const float clf = tg[t * 6 + 1];
        const float cx  = tg[t * 6 + 2];
        const float cy  = tg[t * 6 + 3];
        const float w   = tg[t * 6 + 4];
        const float h   = tg[t * 6 + 5];
        const int b = (int)bi;
        const int cls = (int)clf;

        const int gs = gss[s];
        const float fgs = (float)gs;
        float cxs = cx * fgs, cys = cy * fgs;
        int gi = (int)floorf(cxs); gi = min(max(gi, 0), gs - 1);
        int gj = (int)floorf(cys); gj = min(max(gj, 0), gs - 1);
        const float tx = cxs - (float)gi;
        const float ty = cys - (float)gj;
        const float tw = w * fgs;
        const float th = h * fgs;

        const int hw = gs * gs;
        const float* base = ps[s] + (size_t)b * 18 * hw + (size_t)gj * gs + gi;
        // 18 independent channel loads — one latency round.
        float pr[18];
        #pragma unroll
        for (int ch = 0; ch < 18; ++ch) pr[ch] = base[(size_t)ch * hw];

        const float px = 1.0f / (1.0f + expf(-pr[0]));
        const float py = 1.0f / (1.0f + expf(-pr[1]));
        const float pw = pr[2];
        const float ph = pr[3];

        const float eps = 1e-7f;
        float px1 = px - pw * 0.5f, px2 = px + pw * 0.5f;
        float py1 = py - ph * 0.5f, py2 = py + ph * 0.5f;
        float tx1 = tx - tw * 0.5f, tx2 = tx + tw * 0.5f;
        float ty1 = ty - th * 0.5f, ty2 = ty + th * 0.5f;
        float iw = fmaxf(fminf(px2, tx2) - fmaxf(px1, tx1), 0.0f);
        float ih = fmaxf(fminf(py2, ty2) - fmaxf(py1, ty1), 0.0f);
        float inter = iw * ih;
        float uni = pw * ph + tw * th - inter + eps;
        float iou = inter / uni;
        float ew = fmaxf(fmaxf(px2, tx2) - fminf(px1, tx1), 0.0f);
        float eh = fmaxf(fmaxf(py2, ty2) - fminf(py1, ty1), 0.0f);
        float c2 = ew * ew + eh * eh + eps;
        float rho2 = (px - tx) * (px - tx) + (py - ty) * (py - ty);
        const float four_over_pi2 = 0.405284734569351085775517852f;
        float dat = atanf(tw / (th + eps)) - atanf(pw / (ph + eps));
        float v = four_over_pi2 * dat * dat;
        float alpha = v / (1.0f - iou + v + eps);
        float ciou = iou - (rho2 / c2 + v * alpha);

        v0 = 1.0f - ciou;                                     // box
        float tobj = fmaxf(ciou, 0.0f);
        v1 = focal_term(pr[4], tobj) - focal_term(pr[4], 0.0f);  // obj corr
        #pragma unroll
        for (int k = 0; k < 13; ++k) {                        // cls sum
            float tc = (k == cls) ? 0.95f : 0.0f;
            v2 += bce_fast(pr[5 + k], tc);
        }
    } else if (wid < NBLK_BOX + NBLK_S0 + NBLK_S1) {
        // ---- focal(x,0) sweep s0/s1: 2048 float4/block, 8/thread ----------
        const float* p;
        int hw4, chunk;
        if (wid < NBLK_BOX + NBLK_S0) { p = p0; hw4 = 6400; chunk = wid - NBLK_BOX; }
        else                          { p = p1; hw4 = 1600; chunk = wid - NBLK_BOX - NBLK_S0; }
        int j0 = chunk * 2048 + threadIdx.x;         // float4 idx in scale
        #pragma unroll
        for (int r = 0; r < 8; ++r) {
            int idx = j0 + r * 256;
            int b = idx / hw4;
            int pos4 = idx - b * hw4;
            int hw = hw4 * 4;
            const float4* src = reinterpret_cast<const float4*>(
                p + (size_t)b * 18 * hw + (size_t)4 * hw);
            float4 x = src[pos4];
            v0 += focal0_fast(x.x) + focal0_fast(x.y) +
                  focal0_fast(x.z) + focal0_fast(x.w);
        }
    } else {
        // ---- focal(x,0) sweep s2: 512 float4/block, 2/thread --------------
        int chunk = wid - NBLK_BOX - NBLK_S0 - NBLK_S1;
        const int hw4 = 400, hw = 1600;
        int j0 = chunk * 512 + threadIdx.x;
        #pragma unroll
        for (int r = 0; r < 2; ++r) {
            int idx = j0 + r * 256;
            int b = idx / hw4;
            int pos4 = idx - b * hw4;
            const float4* src = reinterpret_cast<const float4*>(
                p2 + (size_t)b * 18 * hw + (size_t)4 * hw);
            float4 x = src[pos4];
            v0 += focal0_fast(x.x) + focal0_fast(x.y) +
                  focal0_fast(x.z) + focal0_fast(x.w);
        }
    }

    // ---- block reduce, one coalesced float4 store (NO global atomics) -----
    for (int off = 32; off; off >>= 1) {
        v0 += __shfl_down(v0, off);
        v1 += __shfl_down(v1, off);
        v2 += __shfl_down(v2, off);
    }
    if ((threadIdx.x & 63) == 0) {
        sm0[threadIdx.x >> 6] = v0;
        sm1[threadIdx.x >> 6] = v1;
        sm2[threadIdx.x >> 6] = v2;
    }
    __syncthreads();
    if (threadIdx.x == 0) {
        float4 slot;
        slot.x = sm0[0] + sm0[1] + sm0[2] + sm0[3];
        slot.y = sm1[0] + sm1[1] + sm1[2] + sm1[3];
        slot.z = sm2[0] + sm2[1] + sm2[2] + sm2[3];
        slot.w = 0.0f;
        ws4[wid] = slot;
    }
}

__global__ void __launch_bounds__(256) fnl_finalize(
    const float4* __restrict__ ws4, float* __restrict__ out) {
    // acc layout: [s*4 + {0:focal,1:box,2:cls,3:corr}]
    float a[12];
    #pragma unroll
    for (int j = 0; j < 12; ++j) a[j] = 0.0f;

    int i = threadIdx.x;
    if (i < NWORK) {
        float4 v = ws4[i];                            // coalesced 2.4KB read
        if (i < NBLK_BOX) {
            int s = i >> 1;
            a[s * 4 + 1] += v.x;
            a[s * 4 + 3] += v.y;
            a[s * 4 + 2] += v.z;
        } else if (i < NBLK_BOX + NBLK_S0) {
            a[0 * 4 + 0] += v.x;
        } else if (i < NBLK_BOX + NBLK_S0 + NBLK_S1) {
            a[1 * 4 + 0] += v.x;
        } else {
            a[2 * 4 + 0] += v.x;
        }
    }

    __shared__ float red[12];
    if (threadIdx.x < 12) red[threadIdx.x] = 0.0f;
    __syncthreads();
    #pragma unroll
    for (int j = 0; j < 12; ++j) {
        float v = a[j];
        for (int off = 32; off; off >>= 1) v += __shfl_down(v, off);
        if ((threadIdx.x & 63) == 0) atomicAdd(&red[j], v);   // LDS atomic
    }
    __syncthreads();

    if (threadIdx.x == 0) {
        const float cells[3] = {819200.0f, 204800.0f, 51200.0f};
        const float npos = 512.0f;
        float lb = 0.0f, lo = 0.0f, lc = 0.0f;
        for (int s = 0; s < 3; ++s) {
            lb += red[s * 4 + 1] / npos;
            lo += (red[s * 4 + 0] + red[s * 4 + 3]) / cells[s];
            lc += red[s * 4 + 2] / (npos * 13.0f);
        }
        out[0] = 5.0f * lb + 1.0f * lo + 0.5f * lc;
        out[1] = lb;
        out[2] = lo;
        out[3] = lc;
    }
}

extern "C" void kernel_launch(void* const* d_in, const int* in_sizes, int n_in,
                              void* d_out, int out_size, void* d_ws, size_t ws_size,
                              hipStream_t stream) {
    const float* p0 = (const float*)d_in[0];
    const float* p1 = (const float*)d_in[1];
    const float* p2 = (const float*)d_in[2];
    const float* tg = (const float*)d_in[3];
    float4* ws4 = (float4*)d_ws;
    float* out = (float*)d_out;

    fnl_main<<<NWORK, 256, 0, stream>>>(p0, p1, p2, tg, ws4);
    fnl_finalize<<<1, 256, 0, stream>>>(ws4, out);
}